// Round 4
// baseline (322.357 us; speedup 1.0000x reference)
//
#include <hip/hip_runtime.h>
#include <hip/hip_bf16.h>

#define DB 8
#define DN 1024
#define DP 1024
#define DC 256
#define DNS 32
#define DBP (DB * DP)
#define K1 288   // padded GEMM1 K (256 feats + 3 gx + 29 zeros)
#define K2 256
#define XS 296   // x_lds row stride in bf16 elems (592 B; 148 dwords == 20 mod 32)
#define ROWS 128 // 4 bp per block
#define NG (DBP / 4)
#define NK1 (K1 / 16)  // 18
#define NK2 (K2 / 16)  // 16

constexpr float kRadius = 0.05f;
constexpr float kR2 = kRadius * kRadius;
constexpr float kHmin = -0.02f;
constexpr float kHmax = 0.04f;
constexpr float kEps = 1e-5f;
constexpr float kInvCnt = 1.0f / (float)(DB * DP * DNS);

typedef __bf16 bf16x8 __attribute__((ext_vector_type(8)));
typedef float f32x16 __attribute__((ext_vector_type(16)));
static_assert(sizeof(bf16x8) == 16, "bf16x8 must be 16B");

// ---- workspace layout (in floats) ----
constexpr size_t OF_FEATST = 0;                                   // B*N*C bf16
constexpr size_t OF_W1B  = OF_FEATST + (size_t)DB * DN * DC / 2;  // DC*K1 bf16
constexpr size_t OF_W2B  = OF_W1B + (size_t)DC * K1 / 2;          // DC*K2 bf16
constexpr size_t OF_IDX  = OF_W2B + (size_t)DC * K2 / 2;          // BP*NS int32
constexpr size_t OF_GX   = OF_IDX + (size_t)DBP * DNS;            // BP*NS*3
constexpr size_t OF_PART = OF_GX + (size_t)DBP * DNS * 3;         // NG*C*2
constexpr size_t OF_YMAX = OF_PART + (size_t)DBP * DC * 2;        // BP*C
constexpr size_t OF_YMIN = OF_YMAX + (size_t)DBP * DC;            // BP*C
constexpr size_t OF_BN1  = OF_YMIN + (size_t)DBP * DC;            // 512
constexpr size_t OF_BN2  = OF_BN1 + 512;                          // 512

__device__ inline ushort f2b(float x) {
  union { __hip_bfloat16 h; ushort u; } c;
  c.h = __float2bfloat16(x);
  return c.u;
}

// ---------------------------------------------------------------------------
// feats (B,C,N) f32 -> featsTb (B,N,C) bf16 via LDS tile transpose
__global__ void k_transpose_feats(const float* __restrict__ f, uint* __restrict__ ftb) {
  __shared__ float t[32][33];
  int ct = blockIdx.x, nt = blockIdx.y, b = blockIdx.z;
  int tx = threadIdx.x, ty = threadIdx.y;  // 32 x 8
#pragma unroll
  for (int k = 0; k < 4; ++k) {
    int c = ct * 32 + ty + k * 8;
    t[ty + k * 8][tx] = f[((size_t)b * DC + c) * DN + nt * 32 + tx];
  }
  __syncthreads();
  int tid = ty * 32 + tx;
  uint* dst = ftb + (size_t)b * DN * (DC / 2);
#pragma unroll
  for (int it = 0; it < 2; ++it) {
    int idx = it * 256 + tid;
    int nl = idx >> 4, cp = idx & 15;
    uint v = (uint)f2b(t[2 * cp][nl]) | ((uint)f2b(t[2 * cp + 1][nl]) << 16);
    dst[(size_t)(nt * 32 + nl) * (DC / 2) + ct * 16 + cp] = v;
  }
}

// W1 (256,259) f32 -> W1b (256,K1) bf16, K permuted: k'=0..255 <- k=3..258,
// k'=256..258 <- k=0..2 (gx), rest zero
__global__ void k_prep_w1(const float* __restrict__ W1, ushort* __restrict__ W1b) {
  int gid = blockIdx.x * 256 + threadIdx.x;
  if (gid >= DC * K1) return;
  int o = gid / K1, kp = gid - o * K1;
  float v = 0.f;
  if (kp < 256) v = W1[o * 259 + 3 + kp];
  else if (kp < 259) v = W1[o * 259 + (kp - 256)];
  W1b[gid] = f2b(v);
}

__global__ void k_prep_w2(const float* __restrict__ W2, ushort* __restrict__ W2b) {
  int gid = blockIdx.x * 256 + threadIdx.x;
  if (gid >= DC * K2) return;
  W2b[gid] = f2b(W2[gid]);
}

// ---------------------------------------------------------------------------
// cylinder query + grouped/rotated xyz. One wave per (b,p).
__global__ void k_query(const float* __restrict__ xyz, const float* __restrict__ rot,
                        int* __restrict__ idxp, float* __restrict__ gxp) {
  int bp = blockIdx.x;
  int b = bp >> 10;
  int lane = threadIdx.x;
  __shared__ int sidx[DNS];
  __shared__ float srot[9], sc[3];
  if (lane < DNS) sidx[lane] = 0;
  if (lane < 9) srot[lane] = rot[(size_t)bp * 9 + lane];
  if (lane < 3) sc[lane] = xyz[(size_t)bp * 3 + lane];
  __syncthreads();
  float r00 = srot[0], r01 = srot[1], r02 = srot[2];
  float r10 = srot[3], r11 = srot[4], r12 = srot[5];
  float r20 = srot[6], r21 = srot[7], r22 = srot[8];
  float cx = sc[0], cy = sc[1], cz = sc[2];
  const float* xb = xyz + (size_t)b * DN * 3;
  int cnt = 0;
  for (int ch = 0; ch < DN / 64 && cnt < DNS; ++ch) {
    int n = ch * 64 + lane;
    float dx = xb[n * 3 + 0] - cx, dy = xb[n * 3 + 1] - cy, dz = xb[n * 3 + 2] - cz;
    float lx = dx * r00 + dy * r10 + dz * r20;
    float ly = dx * r01 + dy * r11 + dz * r21;
    float lz = dx * r02 + dy * r12 + dz * r22;
    bool m = (ly * ly + lz * lz < kR2) && (lx > kHmin) && (lx < kHmax);
    unsigned long long bal = __ballot(m);
    int rank = cnt + __popcll(bal & ((1ull << lane) - 1ull));
    if (m && rank < DNS) sidx[rank] = n;
    cnt += __popcll(bal);
  }
  __syncthreads();
  if (lane < DNS) {
    int j = sidx[lane];
    idxp[(size_t)bp * DNS + lane] = j;
    float gx = (xb[j * 3 + 0] - cx) / kRadius;
    float gy = (xb[j * 3 + 1] - cy) / kRadius;
    float gz = (xb[j * 3 + 2] - cz) / kRadius;
    float* gp = gxp + ((size_t)bp * DNS + lane) * 3;
    gp[0] = gx * r00 + gy * r10 + gz * r20;
    gp[1] = gx * r01 + gy * r11 + gz * r21;
    gp[2] = gx * r02 + gy * r12 + gz * r22;
  }
}

// ---------------------------------------------------------------------------
// MFMA GEMM over 4 bp per block (128 sample rows), 32x32x16 bf16.
// 256 threads = 4 waves; wave w owns o-range w*64 (2 o-tiles of 32),
// all 4 s-tiles of 32 (s-tile st == bp st).
// A[row=lane&31][k=(lane>>5)*8+j]; B[col=lane&31][k=(lane>>5)*8+j];
// D: col=lane&31, row=(reg&3)+8*(reg>>2)+4*(lane>>5)  [m74/m101].
template <bool FULL>
__global__ __launch_bounds__(256, 2)
void k_gemm(const uint4* __restrict__ ftb, const ushort* __restrict__ W1b,
            const ushort* __restrict__ W2b, const int* __restrict__ idxp,
            const float* __restrict__ gxp, const float* __restrict__ bn1,
            float2* __restrict__ part, float* __restrict__ ymax,
            float* __restrict__ ymin) {
  __shared__ ushort x_lds[ROWS * XS];   // 75776 B, x[s][k] bf16
  __shared__ float bn_lds[2 * DC];

  const int grp = blockIdx.x;           // 0..NG-1
  const int bp0 = grp * 4;
  const int b = bp0 >> 10;
  const int tid = threadIdx.x;
  const int lane = tid & 63;
  const int wv = tid >> 6;
  const int l31 = lane & 31;
  const int l5 = lane >> 5;

  if constexpr (FULL) {
    for (int i = tid; i < 2 * DC; i += 256) bn_lds[i] = bn1[i];
  }

  // ---- gather feats: 128 rows x 512B, 2 threads per row ----
  {
    int s = tid >> 1, q = tid & 1;
    int j = idxp[(size_t)bp0 * DNS + s];
    const uint4* src = ftb + (size_t)(b * DN + j) * (DC / 8) + q * 16;
    uint4* dst = (uint4*)(x_lds + (size_t)s * XS) + q * 16;
#pragma unroll
    for (int k = 0; k < 16; ++k) dst[k] = src[k];
  }
  // ---- gx channels at k=256..258, zeros to 287 ----
  if (tid < ROWS) {
    const float* g = gxp + ((size_t)bp0 * DNS + tid) * 3;
    uint a0 = (uint)f2b(g[0]) | ((uint)f2b(g[1]) << 16);
    uint a1 = (uint)f2b(g[2]);
    uint4* drow = (uint4*)(x_lds + (size_t)tid * XS + 256);
    drow[0] = make_uint4(a0, a1, 0u, 0u);
    drow[1] = make_uint4(0u, 0u, 0u, 0u);
    drow[2] = make_uint4(0u, 0u, 0u, 0u);
    drow[3] = make_uint4(0u, 0u, 0u, 0u);
  }
  __syncthreads();

  f32x16 acc[2][4];
#pragma unroll
  for (int t = 0; t < 2; ++t)
#pragma unroll
    for (int st = 0; st < 4; ++st)
#pragma unroll
      for (int r = 0; r < 16; ++r) acc[t][st][r] = 0.f;

  const int o0 = wv * 64;
  const ushort* xbase = x_lds + (size_t)l31 * XS + l5 * 8;

  // ---- GEMM1: K = 288, 18 K-steps of 16; B 1-deep, A 2-deep prefetch ----
  {
    const ushort* wr[2];
#pragma unroll
    for (int t = 0; t < 2; ++t)
      wr[t] = W1b + (size_t)(o0 + t * 32 + l31) * K1 + l5 * 8;
    bf16x8 aw[2], a1[2], bx[4];
#pragma unroll
    for (int t = 0; t < 2; ++t) aw[t] = *(const bf16x8*)(wr[t]);
#pragma unroll
    for (int t = 0; t < 2; ++t) a1[t] = *(const bf16x8*)(wr[t] + 16);
#pragma unroll
    for (int st = 0; st < 4; ++st)
      bx[st] = *(const bf16x8*)(xbase + (size_t)st * 32 * XS);
#pragma unroll
    for (int ks = 0; ks < NK1; ++ks) {
      bf16x8 bnx[4], a2[2];
      if (ks + 1 < NK1) {
#pragma unroll
        for (int st = 0; st < 4; ++st)
          bnx[st] = *(const bf16x8*)(xbase + (size_t)st * 32 * XS + (ks + 1) * 16);
      }
      if (ks + 2 < NK1) {
#pragma unroll
        for (int t = 0; t < 2; ++t)
          a2[t] = *(const bf16x8*)(wr[t] + (ks + 2) * 16);
      }
#pragma unroll
      for (int st = 0; st < 4; ++st)
#pragma unroll
        for (int t = 0; t < 2; ++t)
          acc[t][st] = __builtin_amdgcn_mfma_f32_32x32x16_bf16(aw[t], bx[st],
                                                               acc[t][st], 0, 0, 0);
      if (ks + 1 < NK1) {
#pragma unroll
        for (int st = 0; st < 4; ++st) bx[st] = bnx[st];
#pragma unroll
        for (int t = 0; t < 2; ++t) aw[t] = a1[t];
      }
      if (ks + 2 < NK1) {
#pragma unroll
        for (int t = 0; t < 2; ++t) a1[t] = a2[t];
      }
    }
  }

  if constexpr (!FULL) {
    // ---- channel sum/sumsq over all 128 rows ----
#pragma unroll
    for (int t = 0; t < 2; ++t) {
#pragma unroll
      for (int r = 0; r < 16; ++r) {
        float s = 0.f, q = 0.f;
#pragma unroll
        for (int st = 0; st < 4; ++st) {
          float v = acc[t][st][r];
          s += v; q += v * v;
        }
#pragma unroll
        for (int m = 1; m < 32; m <<= 1) {
          s += __shfl_xor(s, m, 64);
          q += __shfl_xor(q, m, 64);
        }
        if (l31 == 0) {
          int o = o0 + t * 32 + (r & 3) + 8 * (r >> 2) + 4 * l5;
          part[(size_t)grp * DC + o] = make_float2(s, q);
        }
      }
    }
  } else {
    // ---- bn1 + relu -> x2 (bf16) back into x_lds[s][o] ----
    __syncthreads();  // all GEMM1 LDS reads complete before overwrite
#pragma unroll
    for (int t = 0; t < 2; ++t) {
#pragma unroll
      for (int g = 0; g < 4; ++g) {
        int ob = o0 + t * 32 + 8 * g + 4 * l5;
        float sc0 = bn_lds[ob + 0], sh0 = bn_lds[DC + ob + 0];
        float sc1 = bn_lds[ob + 1], sh1 = bn_lds[DC + ob + 1];
        float sc2 = bn_lds[ob + 2], sh2 = bn_lds[DC + ob + 2];
        float sc3 = bn_lds[ob + 3], sh3 = bn_lds[DC + ob + 3];
#pragma unroll
        for (int st = 0; st < 4; ++st) {
          float v0 = fmaxf(fmaf(acc[t][st][4 * g + 0], sc0, sh0), 0.f);
          float v1 = fmaxf(fmaf(acc[t][st][4 * g + 1], sc1, sh1), 0.f);
          float v2 = fmaxf(fmaf(acc[t][st][4 * g + 2], sc2, sh2), 0.f);
          float v3 = fmaxf(fmaf(acc[t][st][4 * g + 3], sc3, sh3), 0.f);
          uint2 pk = make_uint2((uint)f2b(v0) | ((uint)f2b(v1) << 16),
                                (uint)f2b(v2) | ((uint)f2b(v3) << 16));
          int s = st * 32 + l31;
          *(uint2*)(x_lds + (size_t)s * XS + ob) = pk;
        }
      }
    }
#pragma unroll
    for (int t = 0; t < 2; ++t)
#pragma unroll
      for (int st = 0; st < 4; ++st)
#pragma unroll
        for (int r = 0; r < 16; ++r) acc[t][st][r] = 0.f;
    __syncthreads();

    // ---- GEMM2: K = 256, 16 K-steps ----
    {
      const ushort* wr[2];
#pragma unroll
      for (int t = 0; t < 2; ++t)
        wr[t] = W2b + (size_t)(o0 + t * 32 + l31) * K2 + l5 * 8;
      bf16x8 aw[2], a1[2], bx[4];
#pragma unroll
      for (int t = 0; t < 2; ++t) aw[t] = *(const bf16x8*)(wr[t]);
#pragma unroll
      for (int t = 0; t < 2; ++t) a1[t] = *(const bf16x8*)(wr[t] + 16);
#pragma unroll
      for (int st = 0; st < 4; ++st)
        bx[st] = *(const bf16x8*)(xbase + (size_t)st * 32 * XS);
#pragma unroll
      for (int ks = 0; ks < NK2; ++ks) {
        bf16x8 bnx[4], a2[2];
        if (ks + 1 < NK2) {
#pragma unroll
          for (int st = 0; st < 4; ++st)
            bnx[st] = *(const bf16x8*)(xbase + (size_t)st * 32 * XS + (ks + 1) * 16);
        }
        if (ks + 2 < NK2) {
#pragma unroll
          for (int t = 0; t < 2; ++t)
            a2[t] = *(const bf16x8*)(wr[t] + (ks + 2) * 16);
        }
#pragma unroll
        for (int st = 0; st < 4; ++st)
#pragma unroll
          for (int t = 0; t < 2; ++t)
            acc[t][st] = __builtin_amdgcn_mfma_f32_32x32x16_bf16(aw[t], bx[st],
                                                                 acc[t][st], 0, 0, 0);
        if (ks + 1 < NK2) {
#pragma unroll
          for (int st = 0; st < 4; ++st) bx[st] = bnx[st];
#pragma unroll
          for (int t = 0; t < 2; ++t) aw[t] = a1[t];
        }
        if (ks + 2 < NK2) {
#pragma unroll
          for (int t = 0; t < 2; ++t) a1[t] = a2[t];
        }
      }
    }

    // ---- stats2 (per channel) + per-(bp,o) max/min (s-tile == bp) ----
#pragma unroll
    for (int t = 0; t < 2; ++t) {
#pragma unroll
      for (int r = 0; r < 16; ++r) {
        float s = 0.f, q = 0.f;
        float mx[4], mn[4];
#pragma unroll
        for (int st = 0; st < 4; ++st) {
          float v = acc[t][st][r];
          s += v; q += v * v;
          mx[st] = v; mn[st] = v;
        }
#pragma unroll
        for (int m = 1; m < 32; m <<= 1) {
          s += __shfl_xor(s, m, 64);
          q += __shfl_xor(q, m, 64);
#pragma unroll
          for (int st = 0; st < 4; ++st) {
            mx[st] = fmaxf(mx[st], __shfl_xor(mx[st], m, 64));
            mn[st] = fminf(mn[st], __shfl_xor(mn[st], m, 64));
          }
        }
        if (l31 == 0) {
          int o = o0 + t * 32 + (r & 3) + 8 * (r >> 2) + 4 * l5;
          part[(size_t)grp * DC + o] = make_float2(s, q);
#pragma unroll
          for (int st = 0; st < 4; ++st) {
            ymax[(size_t)(bp0 + st) * DC + o] = mx[st];
            ymin[(size_t)(bp0 + st) * DC + o] = mn[st];
          }
        }
      }
    }
  }
}

// ---------------------------------------------------------------------------
__global__ void k_reduce_bn(const float* __restrict__ part, const float* __restrict__ gam,
                            const float* __restrict__ bet, float* __restrict__ bn) {
  int o = blockIdx.x, tid = threadIdx.x;
  __shared__ float ss[256], sq[256];
  float s = 0.f, q = 0.f;
  const float2* pp = (const float2*)part;
  for (int g = tid; g < NG; g += 256) {
    float2 v = pp[(size_t)g * DC + o];
    s += v.x; q += v.y;
  }
  ss[tid] = s; sq[tid] = q;
  __syncthreads();
  for (int w = 128; w > 0; w >>= 1) {
    if (tid < w) { ss[tid] += ss[tid + w]; sq[tid] += sq[tid + w]; }
    __syncthreads();
  }
  if (tid == 0) {
    float mu = ss[0] * kInvCnt;
    float var = sq[0] * kInvCnt - mu * mu;
    var = var < 0.f ? 0.f : var;
    float sc = gam[o] * rsqrtf(var + kEps);
    bn[o] = sc;
    bn[DC + o] = bet[o] - mu * sc;
  }
}

// ---------------------------------------------------------------------------
__global__ void k_final(const float* __restrict__ ymax, const float* __restrict__ ymin,
                        const float* __restrict__ bn2, float* __restrict__ out) {
  __shared__ float tmax[32][33], tmin[32][33];
  int ot = blockIdx.x, pt = blockIdx.y, b = blockIdx.z;
  int tx = threadIdx.x, ty = threadIdx.y;  // 32 x 8
#pragma unroll
  for (int k = 0; k < 4; ++k) {
    int pr = ty + k * 8;
    size_t base = ((size_t)(b * DP) + pt * 32 + pr) * DC + ot * 32 + tx;
    tmax[pr][tx] = ymax[base];
    tmin[pr][tx] = ymin[base];
  }
  __syncthreads();
#pragma unroll
  for (int k = 0; k < 4; ++k) {
    int oc = ty + k * 8;
    int o = ot * 32 + oc;
    float sc = bn2[o], sh = bn2[DC + o];
    float m = (sc >= 0.f) ? tmax[tx][oc] : tmin[tx][oc];
    float v = fmaf(sc, m, sh);
    v = v > 0.f ? v : 0.f;
    out[((size_t)(b * DC) + o) * DP + pt * 32 + tx] = v;
  }
}

// ---------------------------------------------------------------------------
extern "C" void kernel_launch(void* const* d_in, const int* in_sizes, int n_in,
                              void* d_out, int out_size, void* d_ws, size_t ws_size,
                              hipStream_t stream) {
  const float* xyz   = (const float*)d_in[0];
  const float* feats = (const float*)d_in[1];
  const float* rot   = (const float*)d_in[2];
  const float* W1    = (const float*)d_in[3];
  const float* g1    = (const float*)d_in[4];
  const float* b1    = (const float*)d_in[5];
  const float* W2    = (const float*)d_in[6];
  const float* g2    = (const float*)d_in[7];
  const float* b2    = (const float*)d_in[8];
  float* out = (float*)d_out;

  float* ws = (float*)d_ws;
  uint*   ftb_u  = (uint*)(ws + OF_FEATST);
  uint4*  ftb    = (uint4*)(ws + OF_FEATST);
  ushort* W1b    = (ushort*)(ws + OF_W1B);
  ushort* W2b    = (ushort*)(ws + OF_W2B);
  int*    idxp   = (int*)(ws + OF_IDX);
  float*  gxp    = ws + OF_GX;
  float2* partp  = (float2*)(ws + OF_PART);
  float*  ymaxp  = ws + OF_YMAX;
  float*  yminp  = ws + OF_YMIN;
  float*  bn1p   = ws + OF_BN1;
  float*  bn2p   = ws + OF_BN2;

  k_transpose_feats<<<dim3(DC / 32, DN / 32, DB), dim3(32, 8), 0, stream>>>(feats, ftb_u);
  k_prep_w1<<<(DC * K1 + 255) / 256, 256, 0, stream>>>(W1, W1b);
  k_prep_w2<<<(DC * K2 + 255) / 256, 256, 0, stream>>>(W2, W2b);
  k_query<<<DBP, 64, 0, stream>>>(xyz, rot, idxp, gxp);

  k_gemm<false><<<NG, 256, 0, stream>>>(ftb, W1b, W2b, idxp, gxp, bn1p, partp,
                                        ymaxp, yminp);
  k_reduce_bn<<<DC, 256, 0, stream>>>((const float*)partp, g1, b1, bn1p);
  k_gemm<true><<<NG, 256, 0, stream>>>(ftb, W1b, W2b, idxp, gxp, bn1p, partp,
                                       ymaxp, yminp);
  k_reduce_bn<<<DC, 256, 0, stream>>>((const float*)partp, g2, b2, bn2p);
  k_final<<<dim3(DC / 32, DP / 32, DB), dim3(32, 8), 0, stream>>>(ymaxp, yminp, bn2p, out);
}

// Round 5
// 169.649 us; speedup vs baseline: 1.9001x; 1.9001x over previous
//
#include <hip/hip_runtime.h>
#include <hip/hip_bf16.h>

#define DB 8
#define DN 1024
#define DP 1024
#define DC 256
#define DNS 32
#define DBP (DB * DP)
#define K1 288   // padded GEMM1 K (256 feats + 3 gx + 29 zeros)
#define K2 256
#define XS 296   // x_lds row stride in bf16 elems (592 B; 148 dwords == 20 mod 32)
#define YS 258   // epilogue y-tile row stride in bf16 (129 dwords == 1 mod 32)
#define ROWS 128 // 4 bp per block
#define NG (DBP / 4)
#define NK1 (K1 / 32)  // 9
#define NK2 (K2 / 32)  // 8

constexpr float kRadius = 0.05f;
constexpr float kR2 = kRadius * kRadius;
constexpr float kHmin = -0.02f;
constexpr float kHmax = 0.04f;
constexpr float kEps = 1e-5f;
constexpr float kInvCnt = 1.0f / (float)(DB * DP * DNS);

typedef __bf16 bf16x8 __attribute__((ext_vector_type(8)));
typedef float f32x4 __attribute__((ext_vector_type(4)));
static_assert(sizeof(bf16x8) == 16, "bf16x8 must be 16B");
static_assert(ROWS * XS >= ROWS * YS, "y tile must fit in x_lds");

// ---- workspace layout (in floats) ----
constexpr size_t OF_FEATST = 0;                                   // B*N*C bf16
constexpr size_t OF_W1B  = OF_FEATST + (size_t)DB * DN * DC / 2;  // DC*K1 bf16
constexpr size_t OF_W2B  = OF_W1B + (size_t)DC * K1 / 2;          // DC*K2 bf16
constexpr size_t OF_IDX  = OF_W2B + (size_t)DC * K2 / 2;          // BP*NS int32
constexpr size_t OF_GX   = OF_IDX + (size_t)DBP * DNS;            // BP*NS*3
constexpr size_t OF_PART = OF_GX + (size_t)DBP * DNS * 3;         // NG*C*2
constexpr size_t OF_YMAX = OF_PART + (size_t)DBP * DC * 2;        // BP*C
constexpr size_t OF_YMIN = OF_YMAX + (size_t)DBP * DC;            // BP*C
constexpr size_t OF_BN1  = OF_YMIN + (size_t)DBP * DC;            // 512
constexpr size_t OF_BN2  = OF_BN1 + 512;                          // 512

__device__ inline ushort f2b(float x) {
  union { __hip_bfloat16 h; ushort u; } c;
  c.h = __float2bfloat16(x);
  return c.u;
}
__device__ inline float b2f(ushort u) {
  union { uint u; float f; } c;
  c.u = (uint)u << 16;
  return c.f;
}

// ---------------------------------------------------------------------------
// feats (B,C,N) f32 -> featsTb (B,N,C) bf16 via LDS tile transpose
__global__ void k_transpose_feats(const float* __restrict__ f, uint* __restrict__ ftb) {
  __shared__ float t[32][33];
  int ct = blockIdx.x, nt = blockIdx.y, b = blockIdx.z;
  int tx = threadIdx.x, ty = threadIdx.y;  // 32 x 8
#pragma unroll
  for (int k = 0; k < 4; ++k) {
    int c = ct * 32 + ty + k * 8;
    t[ty + k * 8][tx] = f[((size_t)b * DC + c) * DN + nt * 32 + tx];
  }
  __syncthreads();
  int tid = ty * 32 + tx;
  uint* dst = ftb + (size_t)b * DN * (DC / 2);
#pragma unroll
  for (int it = 0; it < 2; ++it) {
    int idx = it * 256 + tid;
    int nl = idx >> 4, cp = idx & 15;
    uint v = (uint)f2b(t[2 * cp][nl]) | ((uint)f2b(t[2 * cp + 1][nl]) << 16);
    dst[(size_t)(nt * 32 + nl) * (DC / 2) + ct * 16 + cp] = v;
  }
}

// W1 (256,259) f32 -> W1b (256,K1) bf16, K permuted: k'=0..255 <- k=3..258,
// k'=256..258 <- k=0..2 (gx), rest zero
__global__ void k_prep_w1(const float* __restrict__ W1, ushort* __restrict__ W1b) {
  int gid = blockIdx.x * 256 + threadIdx.x;
  if (gid >= DC * K1) return;
  int o = gid / K1, kp = gid - o * K1;
  float v = 0.f;
  if (kp < 256) v = W1[o * 259 + 3 + kp];
  else if (kp < 259) v = W1[o * 259 + (kp - 256)];
  W1b[gid] = f2b(v);
}

__global__ void k_prep_w2(const float* __restrict__ W2, ushort* __restrict__ W2b) {
  int gid = blockIdx.x * 256 + threadIdx.x;
  if (gid >= DC * K2) return;
  W2b[gid] = f2b(W2[gid]);
}

// ---------------------------------------------------------------------------
// cylinder query + grouped/rotated xyz. One wave per (b,p).
__global__ void k_query(const float* __restrict__ xyz, const float* __restrict__ rot,
                        int* __restrict__ idxp, float* __restrict__ gxp) {
  int bp = blockIdx.x;
  int b = bp >> 10;
  int lane = threadIdx.x;
  __shared__ int sidx[DNS];
  __shared__ float srot[9], sc[3];
  if (lane < DNS) sidx[lane] = 0;
  if (lane < 9) srot[lane] = rot[(size_t)bp * 9 + lane];
  if (lane < 3) sc[lane] = xyz[(size_t)bp * 3 + lane];
  __syncthreads();
  float r00 = srot[0], r01 = srot[1], r02 = srot[2];
  float r10 = srot[3], r11 = srot[4], r12 = srot[5];
  float r20 = srot[6], r21 = srot[7], r22 = srot[8];
  float cx = sc[0], cy = sc[1], cz = sc[2];
  const float* xb = xyz + (size_t)b * DN * 3;
  int cnt = 0;
  for (int ch = 0; ch < DN / 64 && cnt < DNS; ++ch) {
    int n = ch * 64 + lane;
    float dx = xb[n * 3 + 0] - cx, dy = xb[n * 3 + 1] - cy, dz = xb[n * 3 + 2] - cz;
    float lx = dx * r00 + dy * r10 + dz * r20;
    float ly = dx * r01 + dy * r11 + dz * r21;
    float lz = dx * r02 + dy * r12 + dz * r22;
    bool m = (ly * ly + lz * lz < kR2) && (lx > kHmin) && (lx < kHmax);
    unsigned long long bal = __ballot(m);
    int rank = cnt + __popcll(bal & ((1ull << lane) - 1ull));
    if (m && rank < DNS) sidx[rank] = n;
    cnt += __popcll(bal);
  }
  __syncthreads();
  if (lane < DNS) {
    int j = sidx[lane];
    idxp[(size_t)bp * DNS + lane] = j;
    float gx = (xb[j * 3 + 0] - cx) / kRadius;
    float gy = (xb[j * 3 + 1] - cy) / kRadius;
    float gz = (xb[j * 3 + 2] - cz) / kRadius;
    float* gp = gxp + ((size_t)bp * DNS + lane) * 3;
    gp[0] = gx * r00 + gy * r10 + gz * r20;
    gp[1] = gx * r01 + gy * r11 + gz * r21;
    gp[2] = gx * r02 + gy * r12 + gz * r22;
  }
}

// ---------------------------------------------------------------------------
// MFMA GEMM over 4 bp per block (128 sample rows), 16x16x32 bf16 (round-3 loop).
// 256 threads = 4 waves; wave w owns o-range w*64 (4 o-tiles of 16), 8 s-tiles.
// D layout: col = lane&15 (=s), row = (lane>>4)*4 + reg (=o).
// Epilogues: acc -> bf16 [s][o] LDS tile (stride YS) -> per-o column reduce.
template <bool FULL>
__global__ __launch_bounds__(256, 2)
void k_gemm(const uint4* __restrict__ ftb, const ushort* __restrict__ W1b,
            const ushort* __restrict__ W2b, const int* __restrict__ idxp,
            const float* __restrict__ gxp, const float* __restrict__ bn1,
            float2* __restrict__ part, float* __restrict__ ymax,
            float* __restrict__ ymin) {
  __shared__ ushort x_lds[ROWS * XS];   // 75776 B; also holds 128x258 y tile
  __shared__ float bn_lds[2 * DC];

  const int grp = blockIdx.x;           // 0..NG-1
  const int bp0 = grp * 4;
  const int b = bp0 >> 10;
  const int tid = threadIdx.x;
  const int lane = tid & 63;
  const int wv = tid >> 6;
  const int l15 = lane & 15;
  const int l4 = lane >> 4;

  if constexpr (FULL) {
    for (int i = tid; i < 2 * DC; i += 256) bn_lds[i] = bn1[i];
  }

  // ---- gather feats: 8 threads/row, 128-B coalesced segments ----
  {
    int q = tid & 7;
#pragma unroll
    for (int rep = 0; rep < 4; ++rep) {
      int s = (tid >> 3) + rep * 32;
      int j = idxp[(size_t)bp0 * DNS + s];
      const uint4* src = ftb + (size_t)(b * DN + j) * (DC / 8);
      uint4* dst = (uint4*)(x_lds + (size_t)s * XS);
#pragma unroll
      for (int k = 0; k < 4; ++k) dst[q + 8 * k] = src[q + 8 * k];
    }
  }
  // ---- gx channels at k=256..258, zeros to 287 ----
  if (tid < ROWS) {
    const float* g = gxp + ((size_t)bp0 * DNS + tid) * 3;
    uint a0 = (uint)f2b(g[0]) | ((uint)f2b(g[1]) << 16);
    uint a1 = (uint)f2b(g[2]);
    uint4* drow = (uint4*)(x_lds + (size_t)tid * XS + 256);
    drow[0] = make_uint4(a0, a1, 0u, 0u);
    drow[1] = make_uint4(0u, 0u, 0u, 0u);
    drow[2] = make_uint4(0u, 0u, 0u, 0u);
    drow[3] = make_uint4(0u, 0u, 0u, 0u);
  }
  __syncthreads();

  f32x4 acc[4][8];
#pragma unroll
  for (int t = 0; t < 4; ++t)
#pragma unroll
    for (int st = 0; st < 8; ++st)
#pragma unroll
      for (int r = 0; r < 4; ++r) acc[t][st][r] = 0.f;

  const int o0 = wv * 64;
  const ushort* xbase = x_lds + (size_t)l15 * XS + l4 * 8;

  // ---- GEMM1: K = 288, 9 K-steps of 32; A prefetched one step ahead ----
  {
    const ushort* wrow[4];
#pragma unroll
    for (int t = 0; t < 4; ++t)
      wrow[t] = W1b + (size_t)(o0 + t * 16 + l15) * K1 + l4 * 8;
    bf16x8 aw[4];
#pragma unroll
    for (int t = 0; t < 4; ++t) aw[t] = *(const bf16x8*)(wrow[t]);
#pragma unroll
    for (int ks = 0; ks < NK1; ++ks) {
      bf16x8 bx[8];
#pragma unroll
      for (int st = 0; st < 8; ++st)
        bx[st] = *(const bf16x8*)(xbase + (size_t)st * 16 * XS + ks * 32);
      bf16x8 an[4];
      if (ks + 1 < NK1) {
#pragma unroll
        for (int t = 0; t < 4; ++t)
          an[t] = *(const bf16x8*)(wrow[t] + (ks + 1) * 32);
      }
#pragma unroll
      for (int st = 0; st < 8; ++st)
#pragma unroll
        for (int t = 0; t < 4; ++t)
          acc[t][st] = __builtin_amdgcn_mfma_f32_16x16x32_bf16(aw[t], bx[st],
                                                               acc[t][st], 0, 0, 0);
      if (ks + 1 < NK1) {
#pragma unroll
        for (int t = 0; t < 4; ++t) aw[t] = an[t];
      }
    }
  }

  if constexpr (!FULL) {
    // ---- y1 -> bf16 [s][o] tile, then per-o column sum/sumsq ----
    __syncthreads();
#pragma unroll
    for (int t = 0; t < 4; ++t) {
      int ob = o0 + t * 16 + l4 * 4;
#pragma unroll
      for (int st = 0; st < 8; ++st) {
        uint2 pk = make_uint2(
            (uint)f2b(acc[t][st][0]) | ((uint)f2b(acc[t][st][1]) << 16),
            (uint)f2b(acc[t][st][2]) | ((uint)f2b(acc[t][st][3]) << 16));
        int s = st * 16 + l15;
        *(uint2*)(x_lds + (size_t)s * YS + ob) = pk;
      }
    }
    __syncthreads();
    {
      const ushort* col = x_lds + tid;  // o = tid
      float s = 0.f, q = 0.f;
#pragma unroll 8
      for (int i = 0; i < ROWS; ++i) {
        float v = b2f(col[(size_t)i * YS]);
        s += v; q += v * v;
      }
      part[(size_t)grp * DC + tid] = make_float2(s, q);
    }
  } else {
    // ---- bn1 + relu -> x2 (bf16) back into x_lds[s][o] (stride XS) ----
    __syncthreads();  // all GEMM1 LDS reads complete before overwrite
#pragma unroll
    for (int t = 0; t < 4; ++t) {
      int ob = o0 + t * 16 + l4 * 4;
      float sc0 = bn_lds[ob + 0], sh0 = bn_lds[DC + ob + 0];
      float sc1 = bn_lds[ob + 1], sh1 = bn_lds[DC + ob + 1];
      float sc2 = bn_lds[ob + 2], sh2 = bn_lds[DC + ob + 2];
      float sc3 = bn_lds[ob + 3], sh3 = bn_lds[DC + ob + 3];
#pragma unroll
      for (int st = 0; st < 8; ++st) {
        float v0 = fmaxf(fmaf(acc[t][st][0], sc0, sh0), 0.f);
        float v1 = fmaxf(fmaf(acc[t][st][1], sc1, sh1), 0.f);
        float v2 = fmaxf(fmaf(acc[t][st][2], sc2, sh2), 0.f);
        float v3 = fmaxf(fmaf(acc[t][st][3], sc3, sh3), 0.f);
        uint2 pk = make_uint2((uint)f2b(v0) | ((uint)f2b(v1) << 16),
                              (uint)f2b(v2) | ((uint)f2b(v3) << 16));
        int s = st * 16 + l15;
        *(uint2*)(x_lds + (size_t)s * XS + ob) = pk;
        acc[t][st][0] = 0.f; acc[t][st][1] = 0.f;
        acc[t][st][2] = 0.f; acc[t][st][3] = 0.f;
      }
    }
    __syncthreads();

    // ---- GEMM2: K = 256, 8 K-steps ----
    {
      const ushort* wrow[4];
#pragma unroll
      for (int t = 0; t < 4; ++t)
        wrow[t] = W2b + (size_t)(o0 + t * 16 + l15) * K2 + l4 * 8;
      bf16x8 aw[4];
#pragma unroll
      for (int t = 0; t < 4; ++t) aw[t] = *(const bf16x8*)(wrow[t]);
#pragma unroll
      for (int ks = 0; ks < NK2; ++ks) {
        bf16x8 bx[8];
#pragma unroll
        for (int st = 0; st < 8; ++st)
          bx[st] = *(const bf16x8*)(xbase + (size_t)st * 16 * XS + ks * 32);
        bf16x8 an[4];
        if (ks + 1 < NK2) {
#pragma unroll
          for (int t = 0; t < 4; ++t)
            an[t] = *(const bf16x8*)(wrow[t] + (ks + 1) * 32);
        }
#pragma unroll
        for (int st = 0; st < 8; ++st)
#pragma unroll
          for (int t = 0; t < 4; ++t)
            acc[t][st] = __builtin_amdgcn_mfma_f32_16x16x32_bf16(aw[t], bx[st],
                                                                 acc[t][st], 0, 0, 0);
        if (ks + 1 < NK2) {
#pragma unroll
          for (int t = 0; t < 4; ++t) aw[t] = an[t];
        }
      }
    }

    // ---- y2 -> bf16 [s][o] tile, then per-o column stats + per-bp max/min ----
    __syncthreads();
#pragma unroll
    for (int t = 0; t < 4; ++t) {
      int ob = o0 + t * 16 + l4 * 4;
#pragma unroll
      for (int st = 0; st < 8; ++st) {
        uint2 pk = make_uint2(
            (uint)f2b(acc[t][st][0]) | ((uint)f2b(acc[t][st][1]) << 16),
            (uint)f2b(acc[t][st][2]) | ((uint)f2b(acc[t][st][3]) << 16));
        int s = st * 16 + l15;
        *(uint2*)(x_lds + (size_t)s * YS + ob) = pk;
      }
    }
    __syncthreads();
    {
      const ushort* col = x_lds + tid;  // o = tid
      float s = 0.f, q = 0.f;
#pragma unroll
      for (int p = 0; p < 4; ++p) {
        float mx = -3.4e38f, mn = 3.4e38f;
#pragma unroll 8
        for (int i = 0; i < DNS; ++i) {
          float v = b2f(col[(size_t)(p * DNS + i) * YS]);
          s += v; q += v * v;
          mx = fmaxf(mx, v); mn = fminf(mn, v);
        }
        ymax[(size_t)(bp0 + p) * DC + tid] = mx;
        ymin[(size_t)(bp0 + p) * DC + tid] = mn;
      }
      part[(size_t)grp * DC + tid] = make_float2(s, q);
    }
  }
}

// ---------------------------------------------------------------------------
__global__ void k_reduce_bn(const float* __restrict__ part, const float* __restrict__ gam,
                            const float* __restrict__ bet, float* __restrict__ bn) {
  int o = blockIdx.x, tid = threadIdx.x;
  __shared__ float ss[256], sq[256];
  float s = 0.f, q = 0.f;
  const float2* pp = (const float2*)part;
  for (int g = tid; g < NG; g += 256) {
    float2 v = pp[(size_t)g * DC + o];
    s += v.x; q += v.y;
  }
  ss[tid] = s; sq[tid] = q;
  __syncthreads();
  for (int w = 128; w > 0; w >>= 1) {
    if (tid < w) { ss[tid] += ss[tid + w]; sq[tid] += sq[tid + w]; }
    __syncthreads();
  }
  if (tid == 0) {
    float mu = ss[0] * kInvCnt;
    float var = sq[0] * kInvCnt - mu * mu;
    var = var < 0.f ? 0.f : var;
    float sc = gam[o] * rsqrtf(var + kEps);
    bn[o] = sc;
    bn[DC + o] = bet[o] - mu * sc;
  }
}

// ---------------------------------------------------------------------------
__global__ void k_final(const float* __restrict__ ymax, const float* __restrict__ ymin,
                        const float* __restrict__ bn2, float* __restrict__ out) {
  __shared__ float tmax[32][33], tmin[32][33];
  int ot = blockIdx.x, pt = blockIdx.y, b = blockIdx.z;
  int tx = threadIdx.x, ty = threadIdx.y;  // 32 x 8
#pragma unroll
  for (int k = 0; k < 4; ++k) {
    int pr = ty + k * 8;
    size_t base = ((size_t)(b * DP) + pt * 32 + pr) * DC + ot * 32 + tx;
    tmax[pr][tx] = ymax[base];
    tmin[pr][tx] = ymin[base];
  }
  __syncthreads();
#pragma unroll
  for (int k = 0; k < 4; ++k) {
    int oc = ty + k * 8;
    int o = ot * 32 + oc;
    float sc = bn2[o], sh = bn2[DC + o];
    float m = (sc >= 0.f) ? tmax[tx][oc] : tmin[tx][oc];
    float v = fmaf(sc, m, sh);
    v = v > 0.f ? v : 0.f;
    out[((size_t)(b * DC) + o) * DP + pt * 32 + tx] = v;
  }
}

// ---------------------------------------------------------------------------
extern "C" void kernel_launch(void* const* d_in, const int* in_sizes, int n_in,
                              void* d_out, int out_size, void* d_ws, size_t ws_size,
                              hipStream_t stream) {
  const float* xyz   = (const float*)d_in[0];
  const float* feats = (const float*)d_in[1];
  const float* rot   = (const float*)d_in[2];
  const float* W1    = (const float*)d_in[3];
  const float* g1    = (const float*)d_in[4];
  const float* b1    = (const float*)d_in[5];
  const float* W2    = (const float*)d_in[6];
  const float* g2    = (const float*)d_in[7];
  const float* b2    = (const float*)d_in[8];
  float* out = (float*)d_out;

  float* ws = (float*)d_ws;
  uint*   ftb_u  = (uint*)(ws + OF_FEATST);
  uint4*  ftb    = (uint4*)(ws + OF_FEATST);
  ushort* W1b    = (ushort*)(ws + OF_W1B);
  ushort* W2b    = (ushort*)(ws + OF_W2B);
  int*    idxp   = (int*)(ws + OF_IDX);
  float*  gxp    = ws + OF_GX;
  float2* partp  = (float2*)(ws + OF_PART);
  float*  ymaxp  = ws + OF_YMAX;
  float*  yminp  = ws + OF_YMIN;
  float*  bn1p   = ws + OF_BN1;
  float*  bn2p   = ws + OF_BN2;

  k_transpose_feats<<<dim3(DC / 32, DN / 32, DB), dim3(32, 8), 0, stream>>>(feats, ftb_u);
  k_prep_w1<<<(DC * K1 + 255) / 256, 256, 0, stream>>>(W1, W1b);
  k_prep_w2<<<(DC * K2 + 255) / 256, 256, 0, stream>>>(W2, W2b);
  k_query<<<DBP, 64, 0, stream>>>(xyz, rot, idxp, gxp);

  k_gemm<false><<<NG, 256, 0, stream>>>(ftb, W1b, W2b, idxp, gxp, bn1p, partp,
                                        ymaxp, yminp);
  k_reduce_bn<<<DC, 256, 0, stream>>>((const float*)partp, g1, b1, bn1p);
  k_gemm<true><<<NG, 256, 0, stream>>>(ftb, W1b, W2b, idxp, gxp, bn1p, partp,
                                       ymaxp, yminp);
  k_reduce_bn<<<DC, 256, 0, stream>>>((const float*)partp, g2, b2, bn2p);
  k_final<<<dim3(DC / 32, DP / 32, DB), dim3(32, 8), 0, stream>>>(ymaxp, yminp, bn2p, out);
}